// Round 10
// baseline (51.260 us; speedup 1.0000x reference)
//
#include <hip/hip_runtime.h>

// Daubechies-4 (db2) synthesis filter taps, f32
#define H_0 0.48296291314469025f
#define H_1 0.8365163037378079f
#define H_2 0.22414386804201336f
#define H_3 (-0.12940952255092145f)
#define G_0 (-0.12940952255092145f)
#define G_1 (-0.22414386804201336f)
#define G_2 0.8365163037378079f
#define G_3 (-0.48296291314469025f)

// Fully-independent patch kernel: one level of inverse db2, fused rows+cols
// pass, NO LDS / barriers / cross-lane ops. Each thread computes a 2x8
// output patch (rows 2m,2m+1, cols [8j,8j+8)) by recomputing the row-pass
// locally for the 5 low + 5 high t-columns it needs (cols 4j-1..4j+3).
// Loads: 8 coalesced float4 + 8 scalar (the scalars hit cache lines fetched
// by the neighbor thread's float4 -> L1/L2 hits, no extra HBM traffic).
// Rationale: thousands of tiny fire-and-forget waves keep reads and writes
// finely interleaved chip-wide (the fillBuffer/copy regime) instead of the
// phase-separated R-burst/W-burst pattern of the earlier LDS/barrier
// variants, which serialized read vs write bandwidth.

template <int S2, bool HS>
__global__ __launch_bounds__(256) void iwt_patch(
    const float* __restrict__ x, int ldx,
    const float* __restrict__ sub, int ldsub,
    float* __restrict__ out, int ldo) {
    constexpr int J = S2 / 4;                 // col-quad tasks per strip
    const int gt = blockIdx.x * 256 + threadIdx.x;
    const int m = gt / J;                     // strip (J is pow2 -> shift)
    const int j = gt & (J - 1);
    const int mp = (m == 0) ? (S2 - 1) : (m - 1);       // circular row wrap
    const int c4 = 4 * j;
    const int cm1 = (j == 0) ? (S2 - 1) : (c4 - 1);     // circular col wrap

    // Source for (rows<S2 x cols<S2) is the previous level's result when HS.
    const float* __restrict__ A = HS ? sub : x;
    const int ldA = HS ? ldsub : ldx;
    const float* __restrict__ rm  = A + (size_t)m  * ldA;        // row m, low cols
    const float* __restrict__ rmp = A + (size_t)mp * ldA;        // row m-1, low cols
    const float* __restrict__ xm  = x + (size_t)m  * ldx + S2;   // row m, high cols
    const float* __restrict__ xmp = x + (size_t)mp * ldx + S2;   // row m-1, high cols
    const float* __restrict__ hm  = x + (size_t)(S2 + m)  * ldx; // row S2+m
    const float* __restrict__ hmp = x + (size_t)(S2 + mp) * ldx; // row S2+m-1

    // 8 coalesced float4 loads + 8 scalar neighbor loads.
    const float4 va = *reinterpret_cast<const float4*>(rm  + c4);
    const float4 vb = *reinterpret_cast<const float4*>(rmp + c4);
    const float4 vc = *reinterpret_cast<const float4*>(hm  + c4);
    const float4 vd = *reinterpret_cast<const float4*>(hmp + c4);
    const float4 ve = *reinterpret_cast<const float4*>(xm  + c4);
    const float4 vf = *reinterpret_cast<const float4*>(xmp + c4);
    const float4 vg = *reinterpret_cast<const float4*>(hm  + S2 + c4);
    const float4 vh = *reinterpret_cast<const float4*>(hmp + S2 + c4);
    const float sa = rm[cm1],  sb = rmp[cm1];
    const float sc = hm[cm1],  sd = hmp[cm1];
    const float se = xm[cm1],  sf = xmp[cm1];
    const float sg = hm[S2 + cm1], sh = hmp[S2 + cm1];

    // Row pass: t rows {2m, 2m+1} at local cols 0..4 (0 = col 4j-1).
    float al[5] = {sa, va.x, va.y, va.z, va.w};   // row m,   low
    float bl[5] = {sb, vb.x, vb.y, vb.z, vb.w};   // row m-1, low
    float cl_[5] = {sc, vc.x, vc.y, vc.z, vc.w};  // row S2+m,   low
    float dl[5] = {sd, vd.x, vd.y, vd.z, vd.w};   // row S2+m-1, low
    float ah[5] = {se, ve.x, ve.y, ve.z, ve.w};   // row m,   high
    float bh[5] = {sf, vf.x, vf.y, vf.z, vf.w};   // row m-1, high
    float ch[5] = {sg, vg.x, vg.y, vg.z, vg.w};   // row S2+m,   high
    float dh[5] = {sh, vh.x, vh.y, vh.z, vh.w};   // row S2+m-1, high

    float tl0[5], tl1[5], th0[5], th1[5];
#pragma unroll
    for (int k = 0; k < 5; ++k) {
        tl0[k] = H_0 * al[k] + H_2 * bl[k] + G_0 * cl_[k] + G_2 * dl[k];
        tl1[k] = H_1 * al[k] + H_3 * bl[k] + G_1 * cl_[k] + G_3 * dl[k];
        th0[k] = H_0 * ah[k] + H_2 * bh[k] + G_0 * ch[k] + G_2 * dh[k];
        th1[k] = H_1 * ah[k] + H_3 * bh[k] + G_1 * ch[k] + G_3 * dh[k];
    }

    // Col pass: out[2m][8j+2i], out[2m][8j+2i+1] from tl0[i+1], tl0[i],
    // th0[i+1], th0[i] (i = 0..3); same for row 2m+1 with tl1/th1.
    float r0[8], r1[8];
#pragma unroll
    for (int i = 0; i < 4; ++i) {
        r0[2 * i]     = H_0 * tl0[i + 1] + H_2 * tl0[i] + G_0 * th0[i + 1] + G_2 * th0[i];
        r0[2 * i + 1] = H_1 * tl0[i + 1] + H_3 * tl0[i] + G_1 * th0[i + 1] + G_3 * th0[i];
        r1[2 * i]     = H_0 * tl1[i + 1] + H_2 * tl1[i] + G_0 * th1[i + 1] + G_2 * th1[i];
        r1[2 * i + 1] = H_1 * tl1[i + 1] + H_3 * tl1[i] + G_1 * th1[i + 1] + G_3 * th1[i];
    }

    float* o0 = out + (size_t)(2 * m) * ldo + 8 * j;
    float* o1 = o0 + ldo;
    *reinterpret_cast<float4*>(o0)     = make_float4(r0[0], r0[1], r0[2], r0[3]);
    *reinterpret_cast<float4*>(o0 + 4) = make_float4(r0[4], r0[5], r0[6], r0[7]);
    *reinterpret_cast<float4*>(o1)     = make_float4(r1[0], r1[1], r1[2], r1[3]);
    *reinterpret_cast<float4*>(o1 + 4) = make_float4(r1[4], r1[5], r1[6], r1[7]);
}

extern "C" void kernel_launch(void* const* d_in, const int* in_sizes, int n_in,
                              void* d_out, int out_size, void* d_ws, size_t ws_size,
                              hipStream_t stream) {
    const float* x = (const float*)d_in[0];   // (1, 4096, 4096) f32
    // d_in[1] = mask, d_in[2] = b : unused; d_in[3] = wavSplit -> levels = 3
    float* out = (float*)d_out;               // 4096 x 4096 f32
    float* buf1 = (float*)d_ws;                                 // 1024^2 f32 (4 MB)
    float* buf2 = (float*)((char*)d_ws + ((size_t)16 << 20));   // 2048^2 f32 (16 MB)

    const int N = 4096;

    // Level 1 (S2=512):  512*128  = 65536 threads  -> 256 blocks.  x -> buf1.
    iwt_patch<512, false><<<256, 256, 0, stream>>>(x, N, nullptr, 0, buf1, 1024);
    // Level 2 (S2=1024): 1024*256 = 262144 threads -> 1024 blocks. buf1 -> buf2.
    iwt_patch<1024, true><<<1024, 256, 0, stream>>>(x, N, buf1, 1024, buf2, 2048);
    // Level 3 (S2=2048): 2048*512 = 1048576 threads -> 4096 blocks. buf2 -> out.
    iwt_patch<2048, true><<<4096, 256, 0, stream>>>(x, N, buf2, 2048, out, N);
}

// Round 11
// 50.409 us; speedup vs baseline: 1.0169x; 1.0169x over previous
//
#include <hip/hip_runtime.h>

// Daubechies-4 (db2) synthesis filter taps, f32
#define H_0 0.48296291314469025f
#define H_1 0.8365163037378079f
#define H_2 0.22414386804201336f
#define H_3 (-0.12940952255092145f)
#define G_0 (-0.12940952255092145f)
#define G_1 (-0.22414386804201336f)
#define G_2 0.8365163037378079f
#define G_3 (-0.48296291314469025f)

// Rolling-stream fused inverse db2 level (register-only, no cross-lane, no
// LDS), with SEG-MAJOR XCD-BANDED block mapping:
//   seg = blockIdx >> 7   (each 128-block band = one 256-t-col panel)
//   m0  = ((blockIdx & 127) * 4 + waveInBlock) * K
// Blocks dispatch round-robin across the 8 XCDs, so a contiguous band of
// blockIdx values - one panel, consecutive strips m - lands on ONE XCD:
// the row-(m-1) inputs re-read by strip m were fetched by strip m-1 on the
// same XCD -> local L2 hits instead of cross-XCD L3 traffic. Row m-1 data
// is also register-carried across the K unrolled iterations (only 4 float4
// + 4 scalar loads per iteration). The col-pass left neighbor t[cl-1] is
// recomputed from 4 scalar loads at input col cl-1 (L1-resident lines).

__device__ __forceinline__ float4 rowpass4(float h0, float h2, float g0, float g2,
                                           const float4& P, const float4& Q,
                                           const float4& R, const float4& T) {
    return make_float4(h0 * P.x + h2 * Q.x + g0 * R.x + g2 * T.x,
                       h0 * P.y + h2 * Q.y + g0 * R.y + g2 * T.y,
                       h0 * P.z + h2 * Q.z + g0 * R.z + g2 * T.z,
                       h0 * P.w + h2 * Q.w + g0 * R.w + g2 * T.w);
}

__device__ __forceinline__ void colpass_store(float* __restrict__ dst,
                                              const float4 L, const float Lm1,
                                              const float4 Hi, const float Hm1) {
    float4 s0, s1;
    s0.x = H_0 * L.x + H_2 * Lm1 + G_0 * Hi.x + G_2 * Hm1;
    s0.y = H_1 * L.x + H_3 * Lm1 + G_1 * Hi.x + G_3 * Hm1;
    s0.z = H_0 * L.y + H_2 * L.x + G_0 * Hi.y + G_2 * Hi.x;
    s0.w = H_1 * L.y + H_3 * L.x + G_1 * Hi.y + G_3 * Hi.x;
    s1.x = H_0 * L.z + H_2 * L.y + G_0 * Hi.z + G_2 * Hi.y;
    s1.y = H_1 * L.z + H_3 * L.y + G_1 * Hi.z + G_3 * Hi.y;
    s1.z = H_0 * L.w + H_2 * L.z + G_0 * Hi.w + G_2 * Hi.z;
    s1.w = H_1 * L.w + H_3 * L.z + G_1 * Hi.w + G_3 * Hi.z;
    *reinterpret_cast<float4*>(dst) = s0;
    *reinterpret_cast<float4*>(dst + 4) = s1;
}

// K: strips per wave (unrolled). Grid = nsegs * 128 blocks; 4 waves/block.
template <int K>
__global__ __launch_bounds__(256) void iwt_band(
    const float* __restrict__ x, int ldx,
    const float* __restrict__ sub, int ldsub,
    float* __restrict__ out, int ldo,
    int S2) {
    const int lane = threadIdx.x & 63;
    const int w = threadIdx.x >> 6;                      // wave in block
    const int seg = blockIdx.x >> 7;                     // 256-t-col panel
    const int mb = blockIdx.x & 127;
    const int m0 = (mb * 4 + w) * K;                     // first strip
    const int cl = (seg << 8) + (lane << 2);             // lane's low t-col
    const int cm1 = (cl == 0) ? (S2 - 1) : (cl - 1);     // t-col cl-1 (wrapped)

    const bool hasSub = (sub != nullptr);
    const float* __restrict__ pA = hasSub ? sub : x;     // rows<S2, cols<S2
    const int ldA = hasSub ? ldsub : ldx;

    // Prologue: row m0-1 inputs (circular wrap only possible here).
    const int mp0 = (m0 == 0) ? (S2 - 1) : (m0 - 1);
    float4 Ap = *reinterpret_cast<const float4*>(pA + (size_t)mp0 * ldA + cl);
    float4 Bp = *reinterpret_cast<const float4*>(x + (size_t)(S2 + mp0) * ldx + cl);
    float4 Cp = *reinterpret_cast<const float4*>(x + (size_t)mp0 * ldx + S2 + cl);
    float4 Dp = *reinterpret_cast<const float4*>(x + (size_t)(S2 + mp0) * ldx + S2 + cl);
    float ap = pA[(size_t)mp0 * ldA + cm1];
    float bp = x[(size_t)(S2 + mp0) * ldx + cm1];
    float cp = x[(size_t)mp0 * ldx + S2 + cm1];
    float dp = x[(size_t)(S2 + mp0) * ldx + S2 + cm1];

#pragma unroll
    for (int i = 0; i < K; ++i) {
        const int m = m0 + i;
        // 4 coalesced float4 loads + 4 per-lane scalar loads (col cl-1).
        const float4 A = *reinterpret_cast<const float4*>(pA + (size_t)m * ldA + cl);
        const float4 B = *reinterpret_cast<const float4*>(x + (size_t)(S2 + m) * ldx + cl);
        const float4 C = *reinterpret_cast<const float4*>(x + (size_t)m * ldx + S2 + cl);
        const float4 D = *reinterpret_cast<const float4*>(x + (size_t)(S2 + m) * ldx + S2 + cl);
        const float a = pA[(size_t)m * ldA + cm1];
        const float b = x[(size_t)(S2 + m) * ldx + cm1];
        const float c = x[(size_t)m * ldx + S2 + cm1];
        const float d = x[(size_t)(S2 + m) * ldx + S2 + cm1];

        // Row pass -> t rows {2m, 2m+1}, low and high col groups.
        const float4 TL0 = rowpass4(H_0, H_2, G_0, G_2, A, Ap, B, Bp);
        const float4 TL1 = rowpass4(H_1, H_3, G_1, G_3, A, Ap, B, Bp);
        const float4 TH0 = rowpass4(H_0, H_2, G_0, G_2, C, Cp, D, Dp);
        const float4 TH1 = rowpass4(H_1, H_3, G_1, G_3, C, Cp, D, Dp);

        // t at col cl-1 (this lane's col-pass left neighbor), rows {2m, 2m+1}.
        const float mL0 = H_0 * a + H_2 * ap + G_0 * b + G_2 * bp;
        const float mL1 = H_1 * a + H_3 * ap + G_1 * b + G_3 * bp;
        const float mH0 = H_0 * c + H_2 * cp + G_0 * d + G_2 * dp;
        const float mH1 = H_1 * c + H_3 * cp + G_1 * d + G_3 * dp;

        // Col pass + store: rows 2m, 2m+1, cols [2*cl, 2*cl+8).
        float* o0 = out + (size_t)(2 * m) * ldo + 2 * cl;
        colpass_store(o0, TL0, mL0, TH0, mH0);
        colpass_store(o0 + ldo, TL1, mL1, TH1, mH1);

        // Roll: current rows become previous rows.
        Ap = A; Bp = B; Cp = C; Dp = D;
        ap = a; bp = b; cp = c; dp = d;
    }
}

extern "C" void kernel_launch(void* const* d_in, const int* in_sizes, int n_in,
                              void* d_out, int out_size, void* d_ws, size_t ws_size,
                              hipStream_t stream) {
    const float* x = (const float*)d_in[0];   // (1, 4096, 4096) f32
    // d_in[1] = mask, d_in[2] = b : unused; d_in[3] = wavSplit -> levels = 3
    float* out = (float*)d_out;               // 4096 x 4096 f32
    float* buf1 = (float*)d_ws;                                 // 1024^2 f32 (4 MB)
    float* buf2 = (float*)((char*)d_ws + ((size_t)16 << 20));   // 2048^2 f32 (16 MB)

    const int N = 4096;

    // Level 1 (S2=512, 2 segs, K=1):  2*128 = 256 blocks,  1024 waves.
    iwt_band<1><<<256, 256, 0, stream>>>(x, N, nullptr, 0, buf1, 1024, 512);
    // Level 2 (S2=1024, 4 segs, K=2): 4*128 = 512 blocks,  2048 waves.
    iwt_band<2><<<512, 256, 0, stream>>>(x, N, buf1, 1024, buf2, 2048, 1024);
    // Level 3 (S2=2048, 8 segs, K=4): 8*128 = 1024 blocks, 4096 waves.
    // Each 128-block band = one 256-t-col panel on one XCD (round-robin
    // dispatch), so strip-to-strip row reuse stays in the local L2.
    iwt_band<4><<<1024, 256, 0, stream>>>(x, N, buf2, 2048, out, N, 2048);
}